// Round 21
// baseline (107.445 us; speedup 1.0000x reference)
//
#include <hip/hip_runtime.h>
#include <hip/hip_bf16.h>

// MoE top-1: N=16384 tokens, D=1024, E=8 experts.
// out[n] = expert_w[argmax(router(x[n]))] @ x[n] + expert_b[e]
//
// Pipeline: k_router (4 tokens/wave in ONE pass: each w-LDS read feeds 16 f64
// FMAs, halving LDS traffic vs the 2-token/2-pass version) -> k_sortconv
// (sort || convw) -> grouped bf16-MFMA GEMM (R16-measured-best: 128^2, BK=64,
// 8 waves, 64 KB dbuf, counted vmcnt(4), raw s_barrier, XCD pinning; 56.2 us).
// GEMM ladder measured: 4w-dbuf 64.4 | 8w-dbuf 56.2* | BK32 65.4 | 256^2 91 |
// 8-phase 76-81 | single-buf 63.3.

#define NTOK 16384
#define DIM  1024
#define NEXP 8

#define AS1 __attribute__((address_space(1)))
#define AS3 __attribute__((address_space(3)))

typedef __bf16 bf16x8 __attribute__((ext_vector_type(8)));
typedef float  f32x4  __attribute__((ext_vector_type(4)));

__device__ __forceinline__ unsigned int f2bf(float f) {
  unsigned int u = __builtin_bit_cast(unsigned int, f);
  u += 0x7FFFu + ((u >> 16) & 1u);   // round-to-nearest-even (finite inputs)
  return u >> 16;
}

// Router: rw (32 KB) staged in LDS once per block. Lane l owns x elements
// {j*256 + 4l .. +4}, j=0..3 (16 B/lane stride => conflict-free ds_read_b128).
// FOUR tokens per wave in a single pass: each w-fragment read serves 16 f64
// FMAs (was 8), halving w-LDS traffic. j-OUTER / e-INNER + sched_barrier(0)
// per j stops cross-j w-load hoisting (VGPR cap). In-lane partials in f64
// (f32 products exact => argmax ground-truth); cross-lane reduce in f32
// (err ~3e-7 << np's own f32 noise). Fused x->bf16. No atomics.
__global__ __launch_bounds__(256) void k_router(const float* __restrict__ x,
                                                const float* __restrict__ rw,
                                                const float* __restrict__ rb,
                                                unsigned short* __restrict__ xbf,
                                                int* __restrict__ top) {
  __shared__ float wlds[NEXP * DIM];   // 32 KB
  const int tid = threadIdx.x;
  const int lane = tid & 63;
  const int wave = tid >> 6;
#pragma unroll
  for (int i = 0; i < 8; ++i)
    ((float4*)wlds)[tid + 256 * i] = ((const float4*)rw)[tid + 256 * i];
  __syncthreads();

  const int ea = lane & 7;
  const float bias = rb[ea];
  const int n0 = (blockIdx.x << 4) + (wave << 2);

  // load 4 tokens x 4 chunks (16 independent 16B loads, deep MLP)
  float4 xv[4][4];
#pragma unroll
  for (int t = 0; t < 4; ++t)
#pragma unroll
    for (int j = 0; j < 4; ++j)
      xv[t][j] = *(const float4*)(x + ((size_t)(n0 + t) << 10) + (j << 8) + (lane << 2));

  // fused bf16 conversion + store: 8 B/lane per (token,chunk), coalesced
#pragma unroll
  for (int t = 0; t < 4; ++t)
#pragma unroll
    for (int j = 0; j < 4; ++j) {
      uint2 s;
      s.x = f2bf(xv[t][j].x) | (f2bf(xv[t][j].y) << 16);
      s.y = f2bf(xv[t][j].z) | (f2bf(xv[t][j].w) << 16);
      *(uint2*)(xbf + ((size_t)(n0 + t) << 10) + (j << 8) + (lane << 2)) = s;
    }

  double p[4][8] = {};
#pragma unroll
  for (int j = 0; j < 4; ++j) {
#pragma unroll
    for (int e = 0; e < 8; ++e) {
      float4 wv = *(const float4*)&wlds[e * 1024 + (j << 8) + (lane << 2)];
#pragma unroll
      for (int t = 0; t < 4; ++t) {
        p[t][e] += (double)xv[t][j].x * (double)wv.x;
        p[t][e] += (double)xv[t][j].y * (double)wv.y;
        p[t][e] += (double)xv[t][j].z * (double)wv.z;
        p[t][e] += (double)xv[t][j].w * (double)wv.w;
      }
    }
    __builtin_amdgcn_sched_barrier(0);   // stop cross-j w-load hoisting
  }

  // f32 cross-lane reduce, 4 independent chains interleave
  float q[4][8];
#pragma unroll
  for (int t = 0; t < 4; ++t)
#pragma unroll
    for (int e = 0; e < 8; ++e) q[t][e] = (float)p[t][e];
#pragma unroll
  for (int e = 0; e < 8; ++e)
#pragma unroll
    for (int t = 0; t < 4; ++t) {
      q[t][e] += __shfl_xor(q[t][e], 1);
      q[t][e] += __shfl_xor(q[t][e], 2);
      q[t][e] += __shfl_xor(q[t][e], 4);
    }
  // static select tree per token (rule #20), then subgroup sum + argmax
  int bi[4];
#pragma unroll
  for (int t = 0; t < 4; ++t) {
    float q0 = (ea & 1) ? q[t][1] : q[t][0], q1 = (ea & 1) ? q[t][3] : q[t][2];
    float q2 = (ea & 1) ? q[t][5] : q[t][4], q3 = (ea & 1) ? q[t][7] : q[t][6];
    float r0 = (ea & 2) ? q1 : q0, r1 = (ea & 2) ? q3 : q2;
    float s  = (ea & 4) ? r1 : r0;
    s += __shfl_xor(s, 8);
    s += __shfl_xor(s, 16);
    s += __shfl_xor(s, 32);
    s += bias;
    // argmax over experts (lane bits 0-2); first index on ties (np.argmax)
    float bv = s;
    int b = ea;
#pragma unroll
    for (int mask = 1; mask <= 4; mask <<= 1) {
      float ov = __shfl_xor(bv, mask);
      int oi = __shfl_xor(b, mask);
      if (ov > bv || (ov == bv && oi < b)) { bv = ov; b = oi; }
    }
    bi[t] = b;
  }
  if (lane == 0) {
    top[n0 + 0] = bi[0];
    top[n0 + 1] = bi[1];
    top[n0 + 2] = bi[2];
    top[n0 + 3] = bi[3];
  }
}

// Merged: block 0 = counting sort (wave-shfl scan, 1 barrier — R15-proven);
// blocks 1..1024 = expert_w f32->bf16 (8 elems/thread) on the other CUs.
__global__ __launch_bounds__(1024) void k_sortconv(const float* __restrict__ ew,
                                                   unsigned short* __restrict__ wbf,
                                                   const int* __restrict__ top,
                                                   int* __restrict__ counts,
                                                   int* __restrict__ tok) {
  const int t = threadIdx.x;
  if (blockIdx.x > 0) {                 // ---- convw part ----
    size_t i = ((size_t)(blockIdx.x - 1) * 1024 + t) * 8;
    const float4* p = (const float4*)(ew + i);
    float4 a = p[0], b = p[1];
    unsigned int w0 = f2bf(a.x) | (f2bf(a.y) << 16);
    unsigned int w1 = f2bf(a.z) | (f2bf(a.w) << 16);
    unsigned int w2 = f2bf(b.x) | (f2bf(b.y) << 16);
    unsigned int w3 = f2bf(b.z) | (f2bf(b.w) << 16);
    *(uint4*)(wbf + i) = make_uint4(w0, w1, w2, w3);
    return;
  }

  // ---- sort part (block 0): per-thread packed-u64 histogram -> per-wave
  // __shfl_up inclusive scan (no barriers) -> 16 wave totals in LDS -> ONE
  // __syncthreads -> predicated base sum -> ordered scatter. Deterministic.
  __shared__ unsigned long long wsum[2][16];
  const int lane = t & 63;
  const int wv = t >> 6;

  int4 v[4];
  const int4* tp = (const int4*)(top + t * 16);
#pragma unroll
  for (int i = 0; i < 4; ++i) v[i] = tp[i];

  unsigned long long h0 = 0, h1 = 0;
#pragma unroll
  for (int i = 0; i < 16; ++i) {
    int e = ((const int*)v)[i];
    if (e < 4) h0 += 1ull << (16 * e);
    else       h1 += 1ull << (16 * (e - 4));
  }

  unsigned long long s0 = h0, s1 = h1;
#pragma unroll
  for (int d = 1; d < 64; d <<= 1) {
    unsigned long long t0 = __shfl_up(s0, d);
    unsigned long long t1 = __shfl_up(s1, d);
    if (lane >= d) { s0 += t0; s1 += t1; }
  }
  if (lane == 63) { wsum[0][wv] = s0; wsum[1][wv] = s1; }
  __syncthreads();

  unsigned long long base0 = 0, base1 = 0;
#pragma unroll
  for (int i = 0; i < 15; ++i) {
    if (i < wv) { base0 += wsum[0][i]; base1 += wsum[1][i]; }
  }
  unsigned long long b0 = base0 + s0 - h0;   // exclusive per-thread base
  unsigned long long b1 = base1 + s1 - h1;

  if (t == 1023) {
    unsigned long long i0 = base0 + s0, i1 = base1 + s1;
#pragma unroll
    for (int e = 0; e < 4; ++e) counts[e] = (int)((i0 >> (16 * e)) & 0xFFFF);
#pragma unroll
    for (int e = 0; e < 4; ++e) counts[4 + e] = (int)((i1 >> (16 * e)) & 0xFFFF);
  }
#pragma unroll
  for (int i = 0; i < 16; ++i) {
    int e = ((const int*)v)[i];
    int pos;
    if (e < 4) {
      pos = (int)((b0 >> (16 * e)) & 0xFFFF);
      b0 += 1ull << (16 * e);
    } else {
      int f = e - 4;
      pos = (int)((b1 >> (16 * f)) & 0xFFFF);
      b1 += 1ull << (16 * f);
    }
    tok[(e << 14) + pos] = t * 16 + i;
  }
}

// Grouped GEMM — R16-measured-best, byte-identical: 128x128 tile, BK=64,
// 8 waves (2M x 4N, wave tile 64x32, acc[4][2]), 2x32 KB dbuf -> 2 blocks/CU
// = 4 waves/SIMD, XOR chunk swizzle (0 conflicts), counted vmcnt(4), raw
// s_barrier pair, expert->XCD pinning (FETCH 36 MB). Measured 56.2 us.
__global__ __launch_bounds__(512, 2) void k_gemm(const unsigned short* __restrict__ xbf,
                                                 const unsigned short* __restrict__ wbf,
                                                 const float* __restrict__ eb,
                                                 const int* __restrict__ counts,
                                                 const int* __restrict__ tokall,
                                                 float* __restrict__ out) {
  const int bid = blockIdx.x;          // 0..8191
  const int e = bid & 7;               // expert == XCD (dispatch round-robins %8)
  const int loc = bid >> 3;            // 0..1023 within XCD
  const int cb = loc & 7;              // col tile (fastest -> temporal locality)
  const int t = loc >> 3;              // token tile 0..127
  const int c = counts[e];
  if (t * 128 >= c) return;
  const int n0 = cb << 7;
  const int* tok = tokall + (e << 14);
  const int tid = threadIdx.x;
  const int lane = tid & 63;
  const int w = tid >> 6;              // wave 0..7
  const int wr = w >> 2;               // 0..1 (M band of 64 rows)
  const int wn = w & 3;                // 0..3 (N band of 32 cols)

  __shared__ unsigned short As[2][128 * 64];  // 2 x 16 KB, chunk-swizzled
  __shared__ unsigned short Bs[2][128 * 64];

  // Staging: per buffer 1024 chunks of 16B; 512 threads x 2 iters.
  // Thread -> (row = s*64 + tid>>3, phys chunk = tid&7); LDS dest linear
  // (s*4096 + w*512 + lane*8 elems == lane*16B from wave base). Swizzle on
  // the GLOBAL source: logical chunk = phys ^ (row&7).
  const int prow = tid >> 3;           // 0..63
  const int pchk = tid & 7;
  size_t asrc[2], bsrc[2];
  const unsigned short* wb = wbf + ((size_t)e << 20);
#pragma unroll
  for (int s = 0; s < 2; ++s) {
    int row = s * 64 + prow;
    int m = t * 128 + row;
    int g = tok[(m < c) ? m : 0];          // pad rows replay token 0 (stores guarded)
    int l = pchk ^ (row & 7);
    asrc[s] = (size_t)g * DIM + (size_t)l * 8;
    bsrc[s] = (size_t)(n0 + row) * DIM + (size_t)l * 8;
  }

  f32x4 acc[4][2] = {};

  // LDS read offsets (elements). A: rows wr*64 + m*16; B: rows wn*32 + n*16.
  int aoff[2][4], boff[2][2];
#pragma unroll
  for (int h = 0; h < 2; ++h) {
#pragma unroll
    for (int m = 0; m < 4; ++m) {
      int row = wr * 64 + m * 16 + (lane & 15);
      int p = (h * 4 + (lane >> 4)) ^ (row & 7);
      aoff[h][m] = row * 64 + p * 8;
    }
#pragma unroll
    for (int n = 0; n < 2; ++n) {
      int rowb = wn * 32 + n * 16 + (lane & 15);
      int pb = (h * 4 + (lane >> 4)) ^ (rowb & 7);
      boff[h][n] = rowb * 64 + pb * 8;
    }
  }

  // stage one K-tile (4 global_load_lds of 16B per thread) into buffer b
  auto stage = [&](int b, int k0) {
#pragma unroll
    for (int s = 0; s < 2; ++s) {
      __builtin_amdgcn_global_load_lds(
          (const AS1 unsigned int*)(xbf + asrc[s] + k0),
          (AS3 unsigned int*)(&As[b][s * 4096 + w * 512]),
          16, 0, 0);
      __builtin_amdgcn_global_load_lds(
          (const AS1 unsigned int*)(wb + bsrc[s] + k0),
          (AS3 unsigned int*)(&Bs[b][s * 4096 + w * 512]),
          16, 0, 0);
    }
  };

  stage(0, 0);                          // 4 loads in flight
  for (int k = 0; k < 16; ++k) {
    if (k < 15) {
      stage((k + 1) & 1, (k + 1) * 64); // 8 in flight
      asm volatile("s_waitcnt vmcnt(4)" ::: "memory");  // current tile landed
    } else {
      asm volatile("s_waitcnt vmcnt(0)" ::: "memory");
    }
    __builtin_amdgcn_s_barrier();       // raw barrier: no compiler vmcnt(0) drain
    __builtin_amdgcn_sched_barrier(0);
    const unsigned short* Ab = As[k & 1];
    const unsigned short* Bb = Bs[k & 1];
#pragma unroll
    for (int h = 0; h < 2; ++h) {
      bf16x8 af[4], bfr[2];
#pragma unroll
      for (int m = 0; m < 4; ++m) af[m] = *(const bf16x8*)&Ab[aoff[h][m]];
#pragma unroll
      for (int n = 0; n < 2; ++n) bfr[n] = *(const bf16x8*)&Bb[boff[h][n]];
#pragma unroll
      for (int m = 0; m < 4; ++m)
#pragma unroll
        for (int n = 0; n < 2; ++n)
          acc[m][n] = __builtin_amdgcn_mfma_f32_16x16x32_bf16(af[m], bfr[n], acc[m][n], 0, 0, 0);
    }
    __builtin_amdgcn_s_barrier();       // all waves done reading before re-stage
  }

  // Epilogue: C/D layout col = lane&15, row = (lane>>4)*4 + reg. Bias + scatter.
  const int colb = n0 + wn * 32 + (lane & 15);
  float bias[2];
#pragma unroll
  for (int n = 0; n < 2; ++n) bias[n] = eb[(e << 10) + colb + n * 16];
#pragma unroll
  for (int m = 0; m < 4; ++m) {
    int rbase = t * 128 + wr * 64 + m * 16 + ((lane >> 4) << 2);
#pragma unroll
    for (int r = 0; r < 4; ++r) {
      int mm = rbase + r;
      if (mm < c) {
        int g = tok[mm];
        float* op = out + ((size_t)g << 10);
#pragma unroll
        for (int n = 0; n < 2; ++n) op[colb + n * 16] = acc[m][n][r] + bias[n];
      }
    }
  }
}

extern "C" void kernel_launch(void* const* d_in, const int* in_sizes, int n_in,
                              void* d_out, int out_size, void* d_ws, size_t ws_size,
                              hipStream_t stream) {
  const float* x  = (const float*)d_in[0];
  const float* rw = (const float*)d_in[1];
  const float* rb = (const float*)d_in[2];
  const float* ew = (const float*)d_in[3];
  const float* eb = (const float*)d_in[4];
  float* out = (float*)d_out;

  char* ws = (char*)d_ws;
  unsigned short* wbf = (unsigned short*)ws;                         // 16 MB
  unsigned short* xbf = (unsigned short*)(ws + (16u << 20));         // 32 MB
  int* tok    = (int*)(ws + (48u << 20));                            // 512 KB
  int* counts = (int*)(ws + (48u << 20) + (1u << 19));               // 32 B
  int* top    = (int*)(ws + (48u << 20) + (1u << 19) + 128);         // 64 KB

  k_router<<<NTOK / 16, 256, 0, stream>>>(x, rw, rb, xbf, top);      // 1024 blocks
  k_sortconv<<<1025, 1024, 0, stream>>>(ew, wbf, top, counts, tok);  // sort || convw
  k_gemm<<<8192, 512, 0, stream>>>(xbf, wbf, eb, counts, tok, out);
}

// Round 22
// 92.572 us; speedup vs baseline: 1.1607x; 1.1607x over previous
//
#include <hip/hip_runtime.h>
#include <hip/hip_bf16.h>

// MoE top-1: N=16384 tokens, D=1024, E=8 experts.
// out[n] = expert_w[argmax(router(x[n]))] @ x[n] + expert_b[e]
//
// BEST-MEASURED COMPOSITION (R16 = 92.7 us), restored verbatim:
//   k_router: 2 tokens/wave/pass, rw in LDS, f64 in-lane dots + f32
//     cross-lane reduce, fused x->bf16  (~20 us; 4-token and interleaved
//     variants both measured slower)
//   k_sortconv: block 0 wave-scan counting sort || blocks 1..1024 W->bf16
//   k_gemm: 128^2 tile, BK=64, 8 waves (2Mx4N), 64 KB dbuf -> 2 blocks/CU,
//     counted vmcnt(4), raw s_barrier, XOR chunk swizzle (0 conflicts),
//     expert->XCD pinning (FETCH 36 MB)  — 56.2 us, best of 7 variants:
//     {4w-dbuf 64.4 | 8w-dbuf 56.2* | BK32 65.4 | 256^2 91 | 8-phase 76-81 |
//      single-buf 63.3}.

#define NTOK 16384
#define DIM  1024
#define NEXP 8

#define AS1 __attribute__((address_space(1)))
#define AS3 __attribute__((address_space(3)))

typedef __bf16 bf16x8 __attribute__((ext_vector_type(8)));
typedef float  f32x4  __attribute__((ext_vector_type(4)));

__device__ __forceinline__ unsigned int f2bf(float f) {
  unsigned int u = __builtin_bit_cast(unsigned int, f);
  u += 0x7FFFu + ((u >> 16) & 1u);   // round-to-nearest-even (finite inputs)
  return u >> 16;
}

// Router: rw (32 KB) staged in LDS once per block. Lane l owns x elements
// {j*256 + 4l .. +4}, j=0..3 (16 B/lane stride => conflict-free ds_read_b128).
// TWO tokens per w-fragment read. j-OUTER / e-INNER with a sched_barrier(0)
// after each j caps live w-fragments (~8 VGPRs). In-lane partials in f64
// (f32 products exact => argmax ground-truth); cross-lane reduce in f32
// (err ~3e-7 << np's own f32 noise). Fused x->bf16. No atomics.
__global__ __launch_bounds__(256) void k_router(const float* __restrict__ x,
                                                const float* __restrict__ rw,
                                                const float* __restrict__ rb,
                                                unsigned short* __restrict__ xbf,
                                                int* __restrict__ top) {
  __shared__ float wlds[NEXP * DIM];   // 32 KB
  const int tid = threadIdx.x;
  const int lane = tid & 63;
  const int wave = tid >> 6;
#pragma unroll
  for (int i = 0; i < 8; ++i)
    ((float4*)wlds)[tid + 256 * i] = ((const float4*)rw)[tid + 256 * i];
  __syncthreads();

  const int ea = lane & 7;
  const float bias = rb[ea];

#pragma unroll 1
  for (int tp = 0; tp < 2; ++tp) {     // two token-pairs per wave (4 tokens)
    const int nA = (blockIdx.x << 4) + (wave << 2) + (tp << 1);
    const int nB = nA + 1;

    float4 xa[4], xb[4];
#pragma unroll
    for (int j = 0; j < 4; ++j) {      // 8 independent 16B loads (deep MLP)
      xa[j] = *(const float4*)(x + ((size_t)nA << 10) + (j << 8) + (lane << 2));
      xb[j] = *(const float4*)(x + ((size_t)nB << 10) + (j << 8) + (lane << 2));
    }

    // fused bf16 conversion + store: 8 B/lane per (token,j), coalesced 512 B
#pragma unroll
    for (int j = 0; j < 4; ++j) {
      uint2 sa, sb;
      sa.x = f2bf(xa[j].x) | (f2bf(xa[j].y) << 16);
      sa.y = f2bf(xa[j].z) | (f2bf(xa[j].w) << 16);
      sb.x = f2bf(xb[j].x) | (f2bf(xb[j].y) << 16);
      sb.y = f2bf(xb[j].z) | (f2bf(xb[j].w) << 16);
      *(uint2*)(xbf + ((size_t)nA << 10) + (j << 8) + (lane << 2)) = sa;
      *(uint2*)(xbf + ((size_t)nB << 10) + (j << 8) + (lane << 2)) = sb;
    }

    double pA[8] = {}, pB[8] = {};
#pragma unroll
    for (int j = 0; j < 4; ++j) {
#pragma unroll
      for (int e = 0; e < 8; ++e) {
        float4 wv = *(const float4*)&wlds[e * 1024 + (j << 8) + (lane << 2)];
        pA[e] += (double)xa[j].x * (double)wv.x;
        pA[e] += (double)xa[j].y * (double)wv.y;
        pA[e] += (double)xa[j].z * (double)wv.z;
        pA[e] += (double)xa[j].w * (double)wv.w;
        pB[e] += (double)xb[j].x * (double)wv.x;
        pB[e] += (double)xb[j].y * (double)wv.y;
        pB[e] += (double)xb[j].z * (double)wv.z;
        pB[e] += (double)xb[j].w * (double)wv.w;
      }
      __builtin_amdgcn_sched_barrier(0);   // stop cross-j w-load hoisting
    }

    // f32 cross-lane reduce (two independent chains interleave)
    float qA[8], qB[8];
#pragma unroll
    for (int e = 0; e < 8; ++e) { qA[e] = (float)pA[e]; qB[e] = (float)pB[e]; }
#pragma unroll
    for (int e = 0; e < 8; ++e) {
      qA[e] += __shfl_xor(qA[e], 1);
      qB[e] += __shfl_xor(qB[e], 1);
      qA[e] += __shfl_xor(qA[e], 2);
      qB[e] += __shfl_xor(qB[e], 2);
      qA[e] += __shfl_xor(qA[e], 4);
      qB[e] += __shfl_xor(qB[e], 4);
    }
    // static select tree: s = q[ea] without runtime indexing (rule #20)
    float sA, sB;
    {
      float q0 = (ea & 1) ? qA[1] : qA[0], q1 = (ea & 1) ? qA[3] : qA[2];
      float q2 = (ea & 1) ? qA[5] : qA[4], q3 = (ea & 1) ? qA[7] : qA[6];
      float r0 = (ea & 2) ? q1 : q0, r1 = (ea & 2) ? q3 : q2;
      sA = (ea & 4) ? r1 : r0;
      q0 = (ea & 1) ? qB[1] : qB[0]; q1 = (ea & 1) ? qB[3] : qB[2];
      q2 = (ea & 1) ? qB[5] : qB[4]; q3 = (ea & 1) ? qB[7] : qB[6];
      r0 = (ea & 2) ? q1 : q0; r1 = (ea & 2) ? q3 : q2;
      sB = (ea & 4) ? r1 : r0;
    }
    sA += __shfl_xor(sA, 8);  sB += __shfl_xor(sB, 8);
    sA += __shfl_xor(sA, 16); sB += __shfl_xor(sB, 16);
    sA += __shfl_xor(sA, 32); sB += __shfl_xor(sB, 32);
    sA += bias; sB += bias;
    // argmax over experts (lane bits 0-2); first index on ties (np.argmax)
    float bvA = sA, bvB = sB;
    int biA = ea, biB = ea;
#pragma unroll
    for (int mask = 1; mask <= 4; mask <<= 1) {
      float ovA = __shfl_xor(bvA, mask), ovB = __shfl_xor(bvB, mask);
      int oiA = __shfl_xor(biA, mask), oiB = __shfl_xor(biB, mask);
      if (ovA > bvA || (ovA == bvA && oiA < biA)) { bvA = ovA; biA = oiA; }
      if (ovB > bvB || (ovB == bvB && oiB < biB)) { bvB = ovB; biB = oiB; }
    }
    if (lane == 0) {
      top[nA] = biA;
      top[nB] = biB;
    }
  }
}

// Merged: block 0 = counting sort (wave-shfl scan, 1 barrier — R15-proven);
// blocks 1..1024 = expert_w f32->bf16 (8 elems/thread) on the other CUs.
__global__ __launch_bounds__(1024) void k_sortconv(const float* __restrict__ ew,
                                                   unsigned short* __restrict__ wbf,
                                                   const int* __restrict__ top,
                                                   int* __restrict__ counts,
                                                   int* __restrict__ tok) {
  const int t = threadIdx.x;
  if (blockIdx.x > 0) {                 // ---- convw part ----
    size_t i = ((size_t)(blockIdx.x - 1) * 1024 + t) * 8;
    const float4* p = (const float4*)(ew + i);
    float4 a = p[0], b = p[1];
    unsigned int w0 = f2bf(a.x) | (f2bf(a.y) << 16);
    unsigned int w1 = f2bf(a.z) | (f2bf(a.w) << 16);
    unsigned int w2 = f2bf(b.x) | (f2bf(b.y) << 16);
    unsigned int w3 = f2bf(b.z) | (f2bf(b.w) << 16);
    *(uint4*)(wbf + i) = make_uint4(w0, w1, w2, w3);
    return;
  }

  // ---- sort part (block 0): per-thread packed-u64 histogram -> per-wave
  // __shfl_up inclusive scan (no barriers) -> 16 wave totals in LDS -> ONE
  // __syncthreads -> predicated base sum -> ordered scatter. Deterministic.
  __shared__ unsigned long long wsum[2][16];
  const int lane = t & 63;
  const int wv = t >> 6;

  int4 v[4];
  const int4* tp = (const int4*)(top + t * 16);
#pragma unroll
  for (int i = 0; i < 4; ++i) v[i] = tp[i];

  unsigned long long h0 = 0, h1 = 0;
#pragma unroll
  for (int i = 0; i < 16; ++i) {
    int e = ((const int*)v)[i];
    if (e < 4) h0 += 1ull << (16 * e);
    else       h1 += 1ull << (16 * (e - 4));
  }

  unsigned long long s0 = h0, s1 = h1;
#pragma unroll
  for (int d = 1; d < 64; d <<= 1) {
    unsigned long long t0 = __shfl_up(s0, d);
    unsigned long long t1 = __shfl_up(s1, d);
    if (lane >= d) { s0 += t0; s1 += t1; }
  }
  if (lane == 63) { wsum[0][wv] = s0; wsum[1][wv] = s1; }
  __syncthreads();

  unsigned long long base0 = 0, base1 = 0;
#pragma unroll
  for (int i = 0; i < 15; ++i) {
    if (i < wv) { base0 += wsum[0][i]; base1 += wsum[1][i]; }
  }
  unsigned long long b0 = base0 + s0 - h0;   // exclusive per-thread base
  unsigned long long b1 = base1 + s1 - h1;

  if (t == 1023) {
    unsigned long long i0 = base0 + s0, i1 = base1 + s1;
#pragma unroll
    for (int e = 0; e < 4; ++e) counts[e] = (int)((i0 >> (16 * e)) & 0xFFFF);
#pragma unroll
    for (int e = 0; e < 4; ++e) counts[4 + e] = (int)((i1 >> (16 * e)) & 0xFFFF);
  }
#pragma unroll
  for (int i = 0; i < 16; ++i) {
    int e = ((const int*)v)[i];
    int pos;
    if (e < 4) {
      pos = (int)((b0 >> (16 * e)) & 0xFFFF);
      b0 += 1ull << (16 * e);
    } else {
      int f = e - 4;
      pos = (int)((b1 >> (16 * f)) & 0xFFFF);
      b1 += 1ull << (16 * f);
    }
    tok[(e << 14) + pos] = t * 16 + i;
  }
}

// Grouped GEMM — R16-measured-best, byte-identical: 128x128 tile, BK=64,
// 8 waves (2M x 4N, wave tile 64x32, acc[4][2]), 2x32 KB dbuf -> 2 blocks/CU
// = 4 waves/SIMD, XOR chunk swizzle (0 conflicts), counted vmcnt(4), raw
// s_barrier pair, expert->XCD pinning (FETCH 36 MB). Measured 56.0-56.2 us.
__global__ __launch_bounds__(512, 2) void k_gemm(const unsigned short* __restrict__ xbf,
                                                 const unsigned short* __restrict__ wbf,
                                                 const float* __restrict__ eb,
                                                 const int* __restrict__ counts,
                                                 const int* __restrict__ tokall,
                                                 float* __restrict__ out) {
  const int bid = blockIdx.x;          // 0..8191
  const int e = bid & 7;               // expert == XCD (dispatch round-robins %8)
  const int loc = bid >> 3;            // 0..1023 within XCD
  const int cb = loc & 7;              // col tile (fastest -> temporal locality)
  const int t = loc >> 3;              // token tile 0..127
  const int c = counts[e];
  if (t * 128 >= c) return;
  const int n0 = cb << 7;
  const int* tok = tokall + (e << 14);
  const int tid = threadIdx.x;
  const int lane = tid & 63;
  const int w = tid >> 6;              // wave 0..7
  const int wr = w >> 2;               // 0..1 (M band of 64 rows)
  const int wn = w & 3;                // 0..3 (N band of 32 cols)

  __shared__ unsigned short As[2][128 * 64];  // 2 x 16 KB, chunk-swizzled
  __shared__ unsigned short Bs[2][128 * 64];

  // Staging: per buffer 1024 chunks of 16B; 512 threads x 2 iters.
  // Thread -> (row = s*64 + tid>>3, phys chunk = tid&7); LDS dest linear
  // (s*4096 + w*512 + lane*8 elems == lane*16B from wave base). Swizzle on
  // the GLOBAL source: logical chunk = phys ^ (row&7).
  const int prow = tid >> 3;           // 0..63
  const int pchk = tid & 7;
  size_t asrc[2], bsrc[2];
  const unsigned short* wb = wbf + ((size_t)e << 20);
#pragma unroll
  for (int s = 0; s < 2; ++s) {
    int row = s * 64 + prow;
    int m = t * 128 + row;
    int g = tok[(m < c) ? m : 0];          // pad rows replay token 0 (stores guarded)
    int l = pchk ^ (row & 7);
    asrc[s] = (size_t)g * DIM + (size_t)l * 8;
    bsrc[s] = (size_t)(n0 + row) * DIM + (size_t)l * 8;
  }

  f32x4 acc[4][2] = {};

  // LDS read offsets (elements). A: rows wr*64 + m*16; B: rows wn*32 + n*16.
  int aoff[2][4], boff[2][2];
#pragma unroll
  for (int h = 0; h < 2; ++h) {
#pragma unroll
    for (int m = 0; m < 4; ++m) {
      int row = wr * 64 + m * 16 + (lane & 15);
      int p = (h * 4 + (lane >> 4)) ^ (row & 7);
      aoff[h][m] = row * 64 + p * 8;
    }
#pragma unroll
    for (int n = 0; n < 2; ++n) {
      int rowb = wn * 32 + n * 16 + (lane & 15);
      int pb = (h * 4 + (lane >> 4)) ^ (rowb & 7);
      boff[h][n] = rowb * 64 + pb * 8;
    }
  }

  // stage one K-tile (4 global_load_lds of 16B per thread) into buffer b
  auto stage = [&](int b, int k0) {
#pragma unroll
    for (int s = 0; s < 2; ++s) {
      __builtin_amdgcn_global_load_lds(
          (const AS1 unsigned int*)(xbf + asrc[s] + k0),
          (AS3 unsigned int*)(&As[b][s * 4096 + w * 512]),
          16, 0, 0);
      __builtin_amdgcn_global_load_lds(
          (const AS1 unsigned int*)(wb + bsrc[s] + k0),
          (AS3 unsigned int*)(&Bs[b][s * 4096 + w * 512]),
          16, 0, 0);
    }
  };

  stage(0, 0);                          // 4 loads in flight
  for (int k = 0; k < 16; ++k) {
    if (k < 15) {
      stage((k + 1) & 1, (k + 1) * 64); // 8 in flight
      asm volatile("s_waitcnt vmcnt(4)" ::: "memory");  // current tile landed
    } else {
      asm volatile("s_waitcnt vmcnt(0)" ::: "memory");
    }
    __builtin_amdgcn_s_barrier();       // raw barrier: no compiler vmcnt(0) drain
    __builtin_amdgcn_sched_barrier(0);
    const unsigned short* Ab = As[k & 1];
    const unsigned short* Bb = Bs[k & 1];
#pragma unroll
    for (int h = 0; h < 2; ++h) {
      bf16x8 af[4], bfr[2];
#pragma unroll
      for (int m = 0; m < 4; ++m) af[m] = *(const bf16x8*)&Ab[aoff[h][m]];
#pragma unroll
      for (int n = 0; n < 2; ++n) bfr[n] = *(const bf16x8*)&Bb[boff[h][n]];
#pragma unroll
      for (int m = 0; m < 4; ++m)
#pragma unroll
        for (int n = 0; n < 2; ++n)
          acc[m][n] = __builtin_amdgcn_mfma_f32_16x16x32_bf16(af[m], bfr[n], acc[m][n], 0, 0, 0);
    }
    __builtin_amdgcn_s_barrier();       // all waves done reading before re-stage
  }

  // Epilogue: C/D layout col = lane&15, row = (lane>>4)*4 + reg. Bias + scatter.
  const int colb = n0 + wn * 32 + (lane & 15);
  float bias[2];
#pragma unroll
  for (int n = 0; n < 2; ++n) bias[n] = eb[(e << 10) + colb + n * 16];
#pragma unroll
  for (int m = 0; m < 4; ++m) {
    int rbase = t * 128 + wr * 64 + m * 16 + ((lane >> 4) << 2);
#pragma unroll
    for (int r = 0; r < 4; ++r) {
      int mm = rbase + r;
      if (mm < c) {
        int g = tok[mm];
        float* op = out + ((size_t)g << 10);
#pragma unroll
        for (int n = 0; n < 2; ++n) op[colb + n * 16] = acc[m][n][r] + bias[n];
      }
    }
  }
}

extern "C" void kernel_launch(void* const* d_in, const int* in_sizes, int n_in,
                              void* d_out, int out_size, void* d_ws, size_t ws_size,
                              hipStream_t stream) {
  const float* x  = (const float*)d_in[0];
  const float* rw = (const float*)d_in[1];
  const float* rb = (const float*)d_in[2];
  const float* ew = (const float*)d_in[3];
  const float* eb = (const float*)d_in[4];
  float* out = (float*)d_out;

  char* ws = (char*)d_ws;
  unsigned short* wbf = (unsigned short*)ws;                         // 16 MB
  unsigned short* xbf = (unsigned short*)(ws + (16u << 20));         // 32 MB
  int* tok    = (int*)(ws + (48u << 20));                            // 512 KB
  int* counts = (int*)(ws + (48u << 20) + (1u << 19));               // 32 B
  int* top    = (int*)(ws + (48u << 20) + (1u << 19) + 128);         // 64 KB

  k_router<<<NTOK / 16, 256, 0, stream>>>(x, rw, rb, xbf, top);      // 1024 blocks
  k_sortconv<<<1025, 1024, 0, stream>>>(ew, wbf, top, counts, tok);  // sort || convw
  k_gemm<<<8192, 512, 0, stream>>>(xbf, wbf, eb, counts, tok, out);
}